// Round 3
// baseline (71.543 us; speedup 1.0000x reference)
//
#include <hip/hip_runtime.h>
#include <hip/hip_cooperative_groups.h>
#include <math.h>

namespace cg = cooperative_groups;

#define BB 384
#define BITS 128
#define NCLS 80
#define NW 3  // 80 bits -> 3 x uint32

// Single fused cooperative kernel:
//  phase 1 (block r): pack labels, ip[r,:], mask, pair loss, loss2 partial
//  grid.sync()
//  phase 2 (block 0): deterministic final reduce -> out[0]
__global__ __launch_bounds__(256) void fused_kernel(
    const float* __restrict__ u,
    const int* __restrict__ y,
    float* __restrict__ contrib,   // [BB]
    float* __restrict__ valid,     // [BB]
    float* __restrict__ l2part,    // [BB]
    float* __restrict__ out)
{
    const int r = blockIdx.x;
    const int tid = threadIdx.x;

    __shared__ float ur[BITS];
    __shared__ float a[BB];
    __shared__ float p[BB];
    __shared__ unsigned int ywsh[BB][NW];
    __shared__ float red[256], red2[256];
    __shared__ int npos_s;

    if (tid < BITS) ur[tid] = u[r * BITS + tid];
    if (tid == 0) npos_s = 0;

    // Pack all label rows into LDS bitmasks (int4-vectorized: 20 loads/row).
    for (int i = tid; i < BB; i += 256) {
        const int4* yi = reinterpret_cast<const int4*>(y + i * NCLS);
        unsigned int w0 = 0, w1 = 0, w2 = 0;
        #pragma unroll
        for (int q = 0; q < 20; ++q) {
            int4 v = yi[q];
            unsigned int bits = (v.x ? 1u : 0u) | (v.y ? 2u : 0u) |
                                (v.z ? 4u : 0u) | (v.w ? 8u : 0u);
            const int c = q * 4;
            if (c < 32)      w0 |= bits << c;
            else if (c < 64) w1 |= bits << (c - 32);
            else             w2 |= bits << (c - 64);
        }
        ywsh[i][0] = w0; ywsh[i][1] = w1; ywsh[i][2] = w2;
    }
    __syncthreads();

    const unsigned int yr0 = ywsh[r][0], yr1 = ywsh[r][1], yr2 = ywsh[r][2];

    int local_pos = 0;
    for (int i = tid; i < BB; i += 256) {
        float acc = 0.f;
        const float* ui = u + i * BITS;
        #pragma unroll 8
        for (int k = 0; k < BITS; k += 4) {
            float4 v = *reinterpret_cast<const float4*>(ui + k);
            acc += ur[k] * v.x + ur[k + 1] * v.y + ur[k + 2] * v.z + ur[k + 3] * v.w;
        }
        a[i] = acc;
        unsigned int s = (yr0 & ywsh[i][0]) | (yr1 & ywsh[i][1]) | (yr2 & ywsh[i][2]);
        p[i] = (s != 0u) ? 1.0f : 0.0f;
        local_pos += (s != 0u) ? 1 : 0;
    }
    if (local_pos) atomicAdd(&npos_s, local_pos);  // int sum: order-independent
    __syncthreads();

    const int n_pos = npos_s;
    const int n_neg = BB - n_pos;
    const float pair_count = (float)n_pos * (float)n_neg;

    float sum = 0.f;
    if (n_pos > 0 && n_neg > 0) {
        for (int i = 0; i < BB; ++i) {
            if (p[i] == 0.f) continue;           // block-uniform skip
            const float ai = a[i] - 0.5f;
            for (int j = tid; j < BB; j += 256) {
                if (p[j] != 0.f) continue;
                float t = ai - a[j];
                t = fminf(fmaxf(t, -100.f), 50.f);
                sum += fmaxf(-t, 0.f) + log1pf(expf(-fabsf(t)));  // softplus(-t)
            }
        }
    }

    // loss2 partial for this row (u[r,:] already in LDS)
    float s2 = 0.f;
    if (tid < BITS) {
        float v = ur[tid];
        float sg = (v > 0.f) ? 1.f : ((v < 0.f) ? -1.f : 0.f);
        float d = v - sg;
        s2 = d * d;
    }

    red[tid] = sum; red2[tid] = s2;
    __syncthreads();
    for (int s = 128; s > 0; s >>= 1) {
        if (tid < s) { red[tid] += red[tid + s]; red2[tid] += red2[tid + s]; }
        __syncthreads();
    }
    if (tid == 0) {
        const bool v = pair_count > 0.f;
        contrib[r] = v ? (red[0] / pair_count) : 0.f;
        valid[r]   = v ? 1.f : 0.f;
        l2part[r]  = red2[0];
    }

    cg::this_grid().sync();

    // Final deterministic reduce on block 0.
    if (r == 0) {
        float s1 = 0.f, s2f = 0.f, c = 0.f;
        for (int i = tid; i < BB; i += 256) {
            s1 += contrib[i]; s2f += l2part[i]; c += valid[i];
        }
        red[tid] = s1; red2[tid] = s2f; p[tid] = c;  // reuse LDS
        __syncthreads();
        for (int s = 128; s > 0; s >>= 1) {
            if (tid < s) { red[tid] += red[tid + s]; red2[tid] += red2[tid + s]; p[tid] += p[tid + s]; }
            __syncthreads();
        }
        if (tid == 0) {
            const float count = p[0];
            const float loss1 = (count > 0.f) ? (red[0] / fmaxf(count, 1.f)) : 0.f;
            const float loss2 = 0.1f * red2[0] / (float)(BB * BITS);
            out[0] = loss1 + loss2;
        }
    }
}

extern "C" void kernel_launch(void* const* d_in, const int* in_sizes, int n_in,
                              void* d_out, int out_size, void* d_ws, size_t ws_size,
                              hipStream_t stream) {
    const float* u = (const float*)d_in[0];
    const int*   y = (const int*)d_in[1];
    float* out = (float*)d_out;

    float* contrib = (float*)d_ws;        // BB floats
    float* valid   = contrib + BB;        // BB floats
    float* l2part  = valid + BB;          // BB floats

    void* args[] = { (void*)&u, (void*)&y, (void*)&contrib,
                     (void*)&valid, (void*)&l2part, (void*)&out };
    hipLaunchCooperativeKernel((const void*)fused_kernel,
                               dim3(BB), dim3(256), args, 0, stream);
}

// Round 4
// 27.062 us; speedup vs baseline: 2.6437x; 2.6437x over previous
//
#include <hip/hip_runtime.h>
#include <math.h>

#define BB 384
#define BITS 128
#define NCLS 80
#define NW 3  // 80 bits -> 3 x uint32

// --- Kernel 1: one block per row r. Packs labels in-block (int4-vectorized),
//     computes ip[r,:], pos mask, pair loss, and loss2 partial. ---
__global__ __launch_bounds__(256) void row_kernel(
    const float* __restrict__ u,
    const int* __restrict__ y,
    float* __restrict__ contrib,   // [BB]
    float* __restrict__ valid,     // [BB]
    float* __restrict__ l2part)    // [BB]
{
    const int r = blockIdx.x;
    const int tid = threadIdx.x;

    __shared__ float ur[BITS];
    __shared__ float a[BB];
    __shared__ float p[BB];
    __shared__ unsigned int ywsh[BB][NW];
    __shared__ float red[256], red2[256];
    __shared__ int npos_s;

    if (tid < BITS) ur[tid] = u[r * BITS + tid];
    if (tid == 0) npos_s = 0;

    // Pack all label rows into LDS bitmasks (20 int4 loads per row).
    for (int i = tid; i < BB; i += 256) {
        const int4* yi = reinterpret_cast<const int4*>(y + i * NCLS);
        unsigned int w0 = 0, w1 = 0, w2 = 0;
        #pragma unroll
        for (int q = 0; q < 20; ++q) {
            int4 v = yi[q];
            unsigned int bits = (v.x ? 1u : 0u) | (v.y ? 2u : 0u) |
                                (v.z ? 4u : 0u) | (v.w ? 8u : 0u);
            const int c = q * 4;
            if (c < 32)      w0 |= bits << c;
            else if (c < 64) w1 |= bits << (c - 32);
            else             w2 |= bits << (c - 64);
        }
        ywsh[i][0] = w0; ywsh[i][1] = w1; ywsh[i][2] = w2;
    }
    __syncthreads();

    const unsigned int yr0 = ywsh[r][0], yr1 = ywsh[r][1], yr2 = ywsh[r][2];

    int local_pos = 0;
    for (int i = tid; i < BB; i += 256) {
        float acc = 0.f;
        const float* ui = u + i * BITS;
        #pragma unroll 8
        for (int k = 0; k < BITS; k += 4) {
            float4 v = *reinterpret_cast<const float4*>(ui + k);
            acc += ur[k] * v.x + ur[k + 1] * v.y + ur[k + 2] * v.z + ur[k + 3] * v.w;
        }
        a[i] = acc;
        unsigned int s = (yr0 & ywsh[i][0]) | (yr1 & ywsh[i][1]) | (yr2 & ywsh[i][2]);
        p[i] = (s != 0u) ? 1.0f : 0.0f;
        local_pos += (s != 0u) ? 1 : 0;
    }
    if (local_pos) atomicAdd(&npos_s, local_pos);  // int sum: order-independent
    __syncthreads();

    const int n_pos = npos_s;
    const int n_neg = BB - n_pos;
    const float pair_count = (float)n_pos * (float)n_neg;

    float sum = 0.f;
    if (n_pos > 0 && n_neg > 0) {
        for (int i = 0; i < BB; ++i) {
            if (p[i] == 0.f) continue;           // block-uniform skip
            const float ai = a[i] - 0.5f;
            for (int j = tid; j < BB; j += 256) {
                if (p[j] != 0.f) continue;
                float t = ai - a[j];
                t = fminf(fmaxf(t, -100.f), 50.f);
                sum += fmaxf(-t, 0.f) + log1pf(expf(-fabsf(t)));  // softplus(-t)
            }
        }
    }

    // loss2 partial for this row (u[r,:] already in LDS)
    float s2 = 0.f;
    if (tid < BITS) {
        float v = ur[tid];
        float sg = (v > 0.f) ? 1.f : ((v < 0.f) ? -1.f : 0.f);
        float d = v - sg;
        s2 = d * d;
    }

    red[tid] = sum; red2[tid] = s2;
    __syncthreads();
    for (int s = 128; s > 0; s >>= 1) {
        if (tid < s) { red[tid] += red[tid + s]; red2[tid] += red2[tid + s]; }
        __syncthreads();
    }
    if (tid == 0) {
        const bool v = pair_count > 0.f;
        contrib[r] = v ? (red[0] / pair_count) : 0.f;
        valid[r]   = v ? 1.f : 0.f;
        l2part[r]  = red2[0];
    }
}

// --- Kernel 2: tiny final deterministic reduction over 3x384 floats. ---
__global__ __launch_bounds__(256) void final_kernel(
    const float* __restrict__ contrib,
    const float* __restrict__ valid,
    const float* __restrict__ l2part,
    float* __restrict__ out)
{
    const int tid = threadIdx.x;
    __shared__ float r1[256], r2[256], rc[256];

    float s1 = 0.f, s2 = 0.f, c = 0.f;
    for (int r = tid; r < BB; r += 256) {
        s1 += contrib[r]; s2 += l2part[r]; c += valid[r];
    }

    r1[tid] = s1; r2[tid] = s2; rc[tid] = c;
    __syncthreads();
    for (int s = 128; s > 0; s >>= 1) {
        if (tid < s) { r1[tid] += r1[tid + s]; r2[tid] += r2[tid + s]; rc[tid] += rc[tid + s]; }
        __syncthreads();
    }
    if (tid == 0) {
        const float count = rc[0];
        const float loss1 = (count > 0.f) ? (r1[0] / fmaxf(count, 1.f)) : 0.f;
        const float loss2 = 0.1f * r2[0] / (float)(BB * BITS);
        out[0] = loss1 + loss2;
    }
}

extern "C" void kernel_launch(void* const* d_in, const int* in_sizes, int n_in,
                              void* d_out, int out_size, void* d_ws, size_t ws_size,
                              hipStream_t stream) {
    const float* u = (const float*)d_in[0];
    const int*   y = (const int*)d_in[1];
    float* out = (float*)d_out;

    float* contrib = (float*)d_ws;        // BB floats
    float* valid   = contrib + BB;        // BB floats
    float* l2part  = valid + BB;          // BB floats

    row_kernel<<<BB, 256, 0, stream>>>(u, y, contrib, valid, l2part);
    final_kernel<<<1, 256, 0, stream>>>(contrib, valid, l2part, out);
}

// Round 5
// 25.447 us; speedup vs baseline: 2.8115x; 1.0635x over previous
//
#include <hip/hip_runtime.h>
#include <math.h>

#define BB 384
#define BITS 128
#define NCLS 80

// Single block, single dispatch. Phases:
//  A: pack labels into LDS bitmasks (threads 0..383)
//  B: per-row positive counts via bit-AND, LDS-broadcast reads (threads 0..767)
//  C: loss2 partial over u, concurrent with B (threads 768..1023)
//  D: per-row validity + valid count
//  E: general path — per-valid-row ip + pair loss (skipped when no valid rows)
//  F: shuffle-tree reduce, write out[0]
__global__ __launch_bounds__(1024) void fused1(
    const float* __restrict__ u,
    const int* __restrict__ y,
    float* __restrict__ out)
{
    const int tid = threadIdx.x;
    const int lane = tid & 63;
    const int wave = tid >> 6;   // 0..15

    __shared__ uint4 yw[BB];       // packed labels (w0,w1,w2,0)
    __shared__ int   nposh[BB][2];
    __shared__ float vflag[BB];
    __shared__ float pcval[BB];
    __shared__ float a[BB];
    __shared__ float urs[BITS];
    __shared__ float wred[16], wred2[16], wredc[16];
    __shared__ int   nvalid_s;

    // --- Phase A: pack ---
    if (tid < BB) {
        const int4* yi = reinterpret_cast<const int4*>(y + tid * NCLS);
        unsigned int w0 = 0, w1 = 0, w2 = 0;
        #pragma unroll
        for (int q = 0; q < 20; ++q) {
            int4 v = yi[q];
            unsigned int bits = (v.x ? 1u : 0u) | (v.y ? 2u : 0u) |
                                (v.z ? 4u : 0u) | (v.w ? 8u : 0u);
            const int c = q * 4;
            if (c < 32)      w0 |= bits << c;
            else if (c < 64) w1 |= bits << (c - 32);
            else             w2 |= bits << (c - 64);
        }
        yw[tid] = make_uint4(w0, w1, w2, 0u);
    }
    __syncthreads();

    float s2 = 0.f;  // loss2 partial
    if (tid < 768) {
        // --- Phase B: counts; thread -> (r = tid>>1, half) ---
        const int r = tid >> 1, h = tid & 1;
        const uint4 yr = yw[r];
        int cnt = 0;
        const int i0 = h * 192;
        #pragma unroll 8
        for (int i = i0; i < i0 + 192; ++i) {
            uint4 wi = yw[i];  // uniform i across lanes -> LDS broadcast
            unsigned int s = (yr.x & wi.x) | (yr.y & wi.y) | (yr.z & wi.z);
            cnt += (s != 0u) ? 1 : 0;
        }
        nposh[r][h] = cnt;
    } else {
        // --- Phase C: loss2, concurrent ---
        const float4* u4 = reinterpret_cast<const float4*>(u);
        for (int idx = tid - 768; idx < BB * BITS / 4; idx += 256) {
            float4 v = u4[idx];
            float d0 = v.x - ((v.x > 0.f) ? 1.f : ((v.x < 0.f) ? -1.f : 0.f));
            float d1 = v.y - ((v.y > 0.f) ? 1.f : ((v.y < 0.f) ? -1.f : 0.f));
            float d2 = v.z - ((v.z > 0.f) ? 1.f : ((v.z < 0.f) ? -1.f : 0.f));
            float d3 = v.w - ((v.w > 0.f) ? 1.f : ((v.w < 0.f) ? -1.f : 0.f));
            s2 += d0 * d0 + d1 * d1 + d2 * d2 + d3 * d3;
        }
    }
    __syncthreads();

    // --- Phase D: validity + count ---
    float cpart = 0.f;
    if (tid < BB) {
        const int np = nposh[tid][0] + nposh[tid][1];
        const int nn = BB - np;
        const float pc = (float)np * (float)nn;
        const bool v = (np > 0) && (nn > 0);
        vflag[tid] = v ? 1.f : 0.f;
        pcval[tid] = v ? pc : 1.f;
        cpart = v ? 1.f : 0.f;
    }
    float c = cpart;
    #pragma unroll
    for (int o = 32; o; o >>= 1) c += __shfl_down(c, o, 64);
    if (lane == 0) wredc[wave] = c;
    __syncthreads();
    if (tid == 0) {
        float t = 0.f;
        #pragma unroll
        for (int w = 0; w < 16; ++w) t += wredc[w];
        nvalid_s = (int)t;
    }
    __syncthreads();
    const int nvalid = nvalid_s;

    // --- Phase E: general path (no valid rows with this data -> skipped) ---
    float s1 = 0.f;
    if (nvalid > 0) {
        for (int rr = 0; rr < BB; ++rr) {
            if (vflag[rr] == 0.f) continue;   // block-uniform branch
            if (tid < BITS) urs[tid] = u[rr * BITS + tid];
            __syncthreads();
            if (tid < BB) {
                const float* ui = u + tid * BITS;
                float acc = 0.f;
                #pragma unroll 8
                for (int k = 0; k < BITS; k += 4) {
                    float4 v = *reinterpret_cast<const float4*>(ui + k);
                    acc += urs[k] * v.x + urs[k+1] * v.y + urs[k+2] * v.z + urs[k+3] * v.w;
                }
                a[tid] = acc;
            }
            __syncthreads();
            const uint4 yrr = yw[rr];
            float part = 0.f;
            for (int i = 0; i < BB; ++i) {
                uint4 wi = yw[i];
                unsigned int sm = (yrr.x & wi.x) | (yrr.y & wi.y) | (yrr.z & wi.z);
                if (sm == 0u) continue;       // i must be positive
                const float ai = a[i] - 0.5f;
                for (int j = tid; j < BB; j += 1024) {
                    uint4 wj = yw[j];
                    unsigned int sj = (yrr.x & wj.x) | (yrr.y & wj.y) | (yrr.z & wj.z);
                    if (sj != 0u) continue;   // j must be negative
                    float t = ai - a[j];
                    t = fminf(fmaxf(t, -100.f), 50.f);
                    part += fmaxf(-t, 0.f) + log1pf(expf(-fabsf(t)));
                }
            }
            s1 += part / pcval[rr];
            __syncthreads();                  // urs/a reused next valid row
        }
    }

    // --- Phase F: final reduce ---
    float v1 = s1, v2 = s2;
    #pragma unroll
    for (int o = 32; o; o >>= 1) {
        v1 += __shfl_down(v1, o, 64);
        v2 += __shfl_down(v2, o, 64);
    }
    if (lane == 0) { wred[wave] = v1; wred2[wave] = v2; }
    __syncthreads();
    if (tid == 0) {
        float S1 = 0.f, S2 = 0.f;
        #pragma unroll
        for (int w = 0; w < 16; ++w) { S1 += wred[w]; S2 += wred2[w]; }
        const float count = (float)nvalid;
        const float loss1 = (count > 0.f) ? (S1 / fmaxf(count, 1.f)) : 0.f;
        const float loss2 = 0.1f * S2 / (float)(BB * BITS);
        out[0] = loss1 + loss2;
    }
}

extern "C" void kernel_launch(void* const* d_in, const int* in_sizes, int n_in,
                              void* d_out, int out_size, void* d_ws, size_t ws_size,
                              hipStream_t stream) {
    const float* u = (const float*)d_in[0];
    const int*   y = (const int*)d_in[1];
    float* out = (float*)d_out;
    fused1<<<1, 1024, 0, stream>>>(u, y, out);
}

// Round 6
// 17.355 us; speedup vs baseline: 4.1223x; 1.4662x over previous
//
#include <hip/hip_runtime.h>
#include <math.h>

#define BB 384
#define BITS 128
#define NCLS 80
#define NB 24
#define RPB (BB / NB)   // 16 rows per block
#define NT 256

// One dispatch, NB blocks. Deterministic last-block-done reduction:
// per-block partials in fixed slots, int counter (order-independent),
// final sum in fixed index order by whichever block arrives last.
__global__ __launch_bounds__(NT) void fused_mb(
    const float* __restrict__ u,
    const int* __restrict__ y,
    float* __restrict__ slots,        // [NB*4]: s1, s2, c, pad
    unsigned int* __restrict__ counter,
    float* __restrict__ out)
{
    const int b = blockIdx.x;
    const int tid = threadIdx.x;

    __shared__ uint4 yw[BB];          // packed labels
    __shared__ float urs[BITS];
    __shared__ float a[BB];
    __shared__ float red[NT], red2[NT];
    __shared__ int   nposs[RPB];

    // --- Phase A: pack all label rows (int4-vectorized, L2-resident) ---
    for (int i = tid; i < BB; i += NT) {
        const int4* yi = reinterpret_cast<const int4*>(y + i * NCLS);
        unsigned int w0 = 0, w1 = 0, w2 = 0;
        #pragma unroll
        for (int q = 0; q < 20; ++q) {
            int4 v = yi[q];
            unsigned int bits = (v.x ? 1u : 0u) | (v.y ? 2u : 0u) |
                                (v.z ? 4u : 0u) | (v.w ? 8u : 0u);
            const int c = q * 4;
            if (c < 32)      w0 |= bits << c;
            else if (c < 64) w1 |= bits << (c - 32);
            else             w2 |= bits << (c - 64);
        }
        yw[i] = make_uint4(w0, w1, w2, 0u);
    }
    __syncthreads();

    // --- Phase B: positive counts for this block's 16 rows ---
    {
        const int rl = tid >> 4;      // 0..15
        const int sub = tid & 15;
        const uint4 yr = yw[b * RPB + rl];
        int cnt = 0;
        #pragma unroll 4
        for (int i = sub; i < BB; i += 16) {
            uint4 wi = yw[i];
            unsigned int s = (yr.x & wi.x) | (yr.y & wi.y) | (yr.z & wi.z);
            cnt += (s != 0u) ? 1 : 0;
        }
        #pragma unroll
        for (int m = 8; m; m >>= 1) cnt += __shfl_xor(cnt, m, 16);
        if (sub == 0) nposs[rl] = cnt;
    }

    // --- loss2 slice: 512 float4 per block (2 per thread) ---
    float s2 = 0.f;
    {
        const float4* u4 = reinterpret_cast<const float4*>(u);
        const int base = b * (BB * BITS / 4 / NB);
        #pragma unroll
        for (int k = 0; k < (BB * BITS / 4 / NB) / NT; ++k) {
            float4 v = u4[base + k * NT + tid];
            float d0 = v.x - ((v.x > 0.f) ? 1.f : ((v.x < 0.f) ? -1.f : 0.f));
            float d1 = v.y - ((v.y > 0.f) ? 1.f : ((v.y < 0.f) ? -1.f : 0.f));
            float d2 = v.z - ((v.z > 0.f) ? 1.f : ((v.z < 0.f) ? -1.f : 0.f));
            float d3 = v.w - ((v.w > 0.f) ? 1.f : ((v.w < 0.f) ? -1.f : 0.f));
            s2 += d0 * d0 + d1 * d1 + d2 * d2 + d3 * d3;
        }
    }
    __syncthreads();

    // --- Phase D/E: per-row validity; general path fully block-local ---
    float s1 = 0.f;
    float cblk = 0.f;                 // uniform across threads
    for (int rl = 0; rl < RPB; ++rl) {
        const int np = nposs[rl];
        const int nn = BB - np;
        if (np <= 0 || nn <= 0) continue;   // block-uniform
        cblk += 1.f;
        const int r = b * RPB + rl;
        const float pc = (float)np * (float)nn;

        if (tid < BITS) urs[tid] = u[r * BITS + tid];
        __syncthreads();
        for (int i = tid; i < BB; i += NT) {
            const float* ui = u + i * BITS;
            float acc = 0.f;
            #pragma unroll 8
            for (int k = 0; k < BITS; k += 4) {
                float4 v = *reinterpret_cast<const float4*>(ui + k);
                acc += urs[k] * v.x + urs[k+1] * v.y + urs[k+2] * v.z + urs[k+3] * v.w;
            }
            a[i] = acc;
        }
        __syncthreads();

        const uint4 yr = yw[r];
        float part = 0.f;
        for (int i = 0; i < BB; ++i) {
            uint4 wi = yw[i];
            if (((yr.x & wi.x) | (yr.y & wi.y) | (yr.z & wi.z)) == 0u) continue;
            const float ai = a[i] - 0.5f;
            for (int j = tid; j < BB; j += NT) {
                uint4 wj = yw[j];
                if (((yr.x & wj.x) | (yr.y & wj.y) | (yr.z & wj.z)) != 0u) continue;
                float t = ai - a[j];
                t = fminf(fmaxf(t, -100.f), 50.f);
                part += fmaxf(-t, 0.f) + log1pf(expf(-fabsf(t)));  // softplus(-t)
            }
        }
        s1 += part / pc;
        __syncthreads();              // urs/a reused by next valid row
    }

    // --- block tree reduce (fixed order) ---
    red[tid] = s1; red2[tid] = s2;
    __syncthreads();
    for (int s = NT / 2; s > 0; s >>= 1) {
        if (tid < s) { red[tid] += red[tid + s]; red2[tid] += red2[tid + s]; }
        __syncthreads();
    }

    // --- publish slot + last-block final reduce ---
    if (tid < 64) {
        unsigned int old = 0;
        if (tid == 0) {
            slots[b * 4 + 0] = red[0];
            slots[b * 4 + 1] = red2[0];
            slots[b * 4 + 2] = cblk;
            __threadfence();
            old = __hip_atomic_fetch_add(counter, 1u, __ATOMIC_ACQ_REL,
                                         __HIP_MEMORY_SCOPE_AGENT);
        }
        old = __shfl(old, 0);
        if (old == NB - 1) {          // all other blocks have published
            float v1 = 0.f, v2 = 0.f, vc = 0.f;
            if (tid < NB) {
                v1 = __hip_atomic_load(&slots[tid * 4 + 0], __ATOMIC_RELAXED,
                                       __HIP_MEMORY_SCOPE_AGENT);
                v2 = __hip_atomic_load(&slots[tid * 4 + 1], __ATOMIC_RELAXED,
                                       __HIP_MEMORY_SCOPE_AGENT);
                vc = __hip_atomic_load(&slots[tid * 4 + 2], __ATOMIC_RELAXED,
                                       __HIP_MEMORY_SCOPE_AGENT);
            }
            #pragma unroll
            for (int o = 32; o; o >>= 1) {
                v1 += __shfl_down(v1, o, 64);
                v2 += __shfl_down(v2, o, 64);
                vc += __shfl_down(vc, o, 64);
            }
            if (tid == 0) {
                const float count = vc;
                const float loss1 = (count > 0.f) ? (v1 / fmaxf(count, 1.f)) : 0.f;
                const float loss2 = 0.1f * v2 / (float)(BB * BITS);
                out[0] = loss1 + loss2;
            }
        }
    }
}

extern "C" void kernel_launch(void* const* d_in, const int* in_sizes, int n_in,
                              void* d_out, int out_size, void* d_ws, size_t ws_size,
                              hipStream_t stream) {
    const float* u = (const float*)d_in[0];
    const int*   y = (const int*)d_in[1];
    float* out = (float*)d_out;

    float* slots = (float*)d_ws;                          // NB*4 floats
    unsigned int* counter = (unsigned int*)(slots + NB * 4);

    hipMemsetAsync(counter, 0, sizeof(unsigned int), stream);  // graph-capturable
    fused_mb<<<NB, NT, 0, stream>>>(u, y, slots, counter, out);
}

// Round 7
// 12.322 us; speedup vs baseline: 5.8060x; 1.4084x over previous
//
#include <hip/hip_runtime.h>
#include <math.h>

#define BB 384
#define BITS 128
#define NCLS 80
#define NB 24
#define RPB (BB / NB)   // 16 rows per block
#define NT 512

// One dispatch, NB blocks, no memset node.
// Completion: blocks 1..NB-1 publish slot + release flag=1; block 0 spins
// (co-resident: 24 blocks << 256 CUs), reduces slots in fixed order, writes
// out, resets flags to 0 for the next graph replay (stream-serialized).
// First call: flags hold 0xAA poison, writers overwrite with 1 during the
// call, spin exits only on ==1 -> correct. Deterministic: fixed-order sums.
__global__ __launch_bounds__(NT) void fused_mb(
    const float* __restrict__ u,
    const int* __restrict__ y,
    float* __restrict__ slots,        // [NB*4]: s1, s2, c, pad
    unsigned int* __restrict__ flags, // [NB]
    float* __restrict__ out)
{
    const int b = blockIdx.x;
    const int tid = threadIdx.x;
    const int lane = tid & 63;
    const int wave = tid >> 6;        // 0..7

    __shared__ uint4 yw[BB];          // packed labels
    __shared__ float urs[BITS];
    __shared__ float a[BB];
    __shared__ float wred[8], wred2[8];
    __shared__ int   nposs[RPB];

    // --- Phase A: pack all label rows (int4-vectorized, L2-resident) ---
    if (tid < BB) {
        const int4* yi = reinterpret_cast<const int4*>(y + tid * NCLS);
        unsigned int w0 = 0, w1 = 0, w2 = 0;
        #pragma unroll
        for (int q = 0; q < 20; ++q) {
            int4 v = yi[q];
            unsigned int bits = (v.x ? 1u : 0u) | (v.y ? 2u : 0u) |
                                (v.z ? 4u : 0u) | (v.w ? 8u : 0u);
            const int c = q * 4;
            if (c < 32)      w0 |= bits << c;
            else if (c < 64) w1 |= bits << (c - 32);
            else             w2 |= bits << (c - 64);
        }
        yw[tid] = make_uint4(w0, w1, w2, 0u);
    }

    // --- loss2 slice: exactly one float4 per thread (24*512 = 12288) ---
    float s2 = 0.f;
    {
        const float4* u4 = reinterpret_cast<const float4*>(u);
        float4 v = u4[b * NT + tid];
        float d0 = v.x - ((v.x > 0.f) ? 1.f : ((v.x < 0.f) ? -1.f : 0.f));
        float d1 = v.y - ((v.y > 0.f) ? 1.f : ((v.y < 0.f) ? -1.f : 0.f));
        float d2 = v.z - ((v.z > 0.f) ? 1.f : ((v.z < 0.f) ? -1.f : 0.f));
        float d3 = v.w - ((v.w > 0.f) ? 1.f : ((v.w < 0.f) ? -1.f : 0.f));
        s2 = d0 * d0 + d1 * d1 + d2 * d2 + d3 * d3;
    }
    __syncthreads();

    // --- Phase B: positive counts for this block's 16 rows (32 lanes/row) ---
    {
        const int rl = tid >> 5;      // 0..15
        const int sub = tid & 31;
        const uint4 yr = yw[b * RPB + rl];
        int cnt = 0;
        #pragma unroll 4
        for (int i = sub; i < BB; i += 32) {
            uint4 wi = yw[i];
            unsigned int s = (yr.x & wi.x) | (yr.y & wi.y) | (yr.z & wi.z);
            cnt += (s != 0u) ? 1 : 0;
        }
        #pragma unroll
        for (int m = 16; m; m >>= 1) cnt += __shfl_xor(cnt, m, 32);
        if (sub == 0) nposs[rl] = cnt;
    }
    __syncthreads();

    // --- Phase D/E: per-row validity; general path fully block-local ---
    float s1 = 0.f;
    float cblk = 0.f;                 // uniform across threads
    for (int rl = 0; rl < RPB; ++rl) {
        const int np = nposs[rl];
        const int nn = BB - np;
        if (np <= 0 || nn <= 0) continue;   // block-uniform
        cblk += 1.f;
        const int r = b * RPB + rl;
        const float pc = (float)np * (float)nn;

        if (tid < BITS) urs[tid] = u[r * BITS + tid];
        __syncthreads();
        if (tid < BB) {
            const float* ui = u + tid * BITS;
            float acc = 0.f;
            #pragma unroll 8
            for (int k = 0; k < BITS; k += 4) {
                float4 v = *reinterpret_cast<const float4*>(ui + k);
                acc += urs[k] * v.x + urs[k+1] * v.y + urs[k+2] * v.z + urs[k+3] * v.w;
            }
            a[tid] = acc;
        }
        __syncthreads();

        const uint4 yr = yw[r];
        float part = 0.f;
        for (int i = 0; i < BB; ++i) {
            uint4 wi = yw[i];
            if (((yr.x & wi.x) | (yr.y & wi.y) | (yr.z & wi.z)) == 0u) continue;
            const float ai = a[i] - 0.5f;
            for (int j = tid; j < BB; j += NT) {
                uint4 wj = yw[j];
                if (((yr.x & wj.x) | (yr.y & wj.y) | (yr.z & wj.z)) != 0u) continue;
                float t = ai - a[j];
                t = fminf(fmaxf(t, -100.f), 50.f);
                part += fmaxf(-t, 0.f) + log1pf(expf(-fabsf(t)));  // softplus(-t)
            }
        }
        s1 += part / pc;
        __syncthreads();              // urs/a reused by next valid row
    }

    // --- block reduce: wave shuffle + 8-slot LDS (fixed order) ---
    float v1 = s1, v2 = s2;
    #pragma unroll
    for (int o = 32; o; o >>= 1) {
        v1 += __shfl_down(v1, o, 64);
        v2 += __shfl_down(v2, o, 64);
    }
    if (lane == 0) { wred[wave] = v1; wred2[wave] = v2; }
    __syncthreads();

    // --- publish slot (+flag for b>0) ---
    if (tid == 0) {
        float S1 = 0.f, S2 = 0.f;
        #pragma unroll
        for (int w = 0; w < 8; ++w) { S1 += wred[w]; S2 += wred2[w]; }
        __hip_atomic_store(&slots[b * 4 + 0], S1, __ATOMIC_RELAXED, __HIP_MEMORY_SCOPE_AGENT);
        __hip_atomic_store(&slots[b * 4 + 1], S2, __ATOMIC_RELAXED, __HIP_MEMORY_SCOPE_AGENT);
        __hip_atomic_store(&slots[b * 4 + 2], cblk, __ATOMIC_RELAXED, __HIP_MEMORY_SCOPE_AGENT);
        if (b != 0)
            __hip_atomic_store(&flags[b], 1u, __ATOMIC_RELEASE, __HIP_MEMORY_SCOPE_AGENT);
    }

    // --- block 0: wait, reduce all slots in fixed lane order, write out ---
    if (b == 0) {
        if (tid > 0 && tid < NB) {
            while (__hip_atomic_load(&flags[tid], __ATOMIC_ACQUIRE,
                                     __HIP_MEMORY_SCOPE_AGENT) != 1u) {}
        }
        __syncthreads();
        if (tid < 64) {
            float r1 = 0.f, r2 = 0.f, rc = 0.f;
            if (tid < NB) {
                r1 = __hip_atomic_load(&slots[tid * 4 + 0], __ATOMIC_RELAXED, __HIP_MEMORY_SCOPE_AGENT);
                r2 = __hip_atomic_load(&slots[tid * 4 + 1], __ATOMIC_RELAXED, __HIP_MEMORY_SCOPE_AGENT);
                rc = __hip_atomic_load(&slots[tid * 4 + 2], __ATOMIC_RELAXED, __HIP_MEMORY_SCOPE_AGENT);
            }
            #pragma unroll
            for (int o = 32; o; o >>= 1) {
                r1 += __shfl_down(r1, o, 64);
                r2 += __shfl_down(r2, o, 64);
                rc += __shfl_down(rc, o, 64);
            }
            if (tid == 0) {
                const float count = rc;
                const float loss1 = (count > 0.f) ? (r1 / fmaxf(count, 1.f)) : 0.f;
                const float loss2 = 0.1f * r2 / (float)(BB * BITS);
                out[0] = loss1 + loss2;
            }
            if (tid > 0 && tid < NB)  // reset for next replay (stream-serialized)
                __hip_atomic_store(&flags[tid], 0u, __ATOMIC_RELAXED, __HIP_MEMORY_SCOPE_AGENT);
        }
    }
}

extern "C" void kernel_launch(void* const* d_in, const int* in_sizes, int n_in,
                              void* d_out, int out_size, void* d_ws, size_t ws_size,
                              hipStream_t stream) {
    const float* u = (const float*)d_in[0];
    const int*   y = (const int*)d_in[1];
    float* out = (float*)d_out;

    float* slots = (float*)d_ws;                          // NB*4 floats
    unsigned int* flags = (unsigned int*)(slots + NB * 4); // NB words

    fused_mb<<<NB, NT, 0, stream>>>(u, y, slots, flags, out);
}